// Round 12
// baseline (158.095 us; speedup 1.0000x reference)
//
#include <hip/hip_runtime.h>
#include <hip/hip_bf16.h>

// B=16, T=12, N=1024, F_IN=F_OUT=64, K=3
#define BB 16
#define TT 12
#define NN 1024
#define FF 64
#define KC 3

typedef __bf16  bf16x8 __attribute__((ext_vector_type(8)));
typedef float   f32x4  __attribute__((ext_vector_type(4)));
typedef float   f32x16 __attribute__((ext_vector_type(16)));
typedef unsigned short u16;

#define A_TILE 24576   // one (b,it,jt) A tile: 3k * 64row * 128B
#define Y_TILE 32768   // 4 bt * 8192 B (one jt)
#define MFMA_B(a, b, c) __builtin_amdgcn_mfma_f32_32x32x16_bf16(a, b, c, 0, 0, 0)

// ws tiers:
//  tier1: yfr (25165824) + A_ws (16*16*16*24576 = 100663296) = 125829120
//  tier2: yfr (25165824) + cheb_bf (6291456) = 31457280
#define YF_BYTES 25165824ull
#define AW_BYTES 100663296ull
#define CB_BYTES 6291456ull
#define T1_BYTES (YF_BYTES + AW_BYTES)
#define T2_BYTES (YF_BYTES + CB_BYTES)

static __device__ __forceinline__ u16 f2bf(float v) {
    union { __bf16 b; u16 u; } c; c.b = (__bf16)v; return c.u;
}

static __device__ __forceinline__ void load_lds16(const void* g, void* l) {
    __builtin_amdgcn_global_load_lds(
        (const __attribute__((address_space(1))) unsigned int*)g,
        (__attribute__((address_space(3))) unsigned int*)l, 16, 0, 0);
}

// ---------------- prepass 1: x [B,T,N,F] f32 -> y_frags bf16 (proven) -------
__global__ __launch_bounds__(256) void x_to_yfrags(
    const float* __restrict__ x, u16* __restrict__ y)
{
    __shared__ char tl[64 * 128];
    const int tid = threadIdx.x;
    const int bt  = blockIdx.x >> 4;
    const int jt  = blockIdx.x & 15;
    const int f   = tid & 63;
    const int jr  = tid >> 6;

    const float* xp = x + ((size_t)bt * NN + jt * 64 + jr) * FF + f;
    #pragma unroll
    for (int stp = 0; stp < 16; ++stp) {
        int j = stp * 4 + jr;
        u16 h = f2bf(xp[stp * 4 * FF]);
        *reinterpret_cast<u16*>(tl + j * 128 + ((f * 2) ^ ((j & 7) << 4))) = h;
    }
    __syncthreads();

    u16* yo = y + ((size_t)bt * 16 + jt) * 4096;
    #pragma unroll
    for (int p = 0; p < 2; ++p) {
        int c  = tid + p * 256;
        int s  = c >> 6, fo = c & 63;
        int j0 = (s >> 1) * 16 + (s & 1) * 8;
        u16 h[8];
        #pragma unroll
        for (int e = 0; e < 8; ++e)
            h[e] = *reinterpret_cast<u16*>(tl + (j0 + e) * 128 + ((fo * 2) ^ (e << 4)));
        uint4 w;
        w.x = h[0] | ((unsigned)h[1] << 16);
        w.y = h[2] | ((unsigned)h[3] << 16);
        w.z = h[4] | ((unsigned)h[5] << 16);
        w.w = h[6] | ((unsigned)h[7] << 16);
        *reinterpret_cast<uint4*>(yo + (size_t)c * 8) = w;
    }
}

// ---------------- tier1 prepass: build A = cheb*att, swizzled fragment image -
// ws tile (b,it,jt) 24576 B; byte (k*64+row)*128 + ((jg<<4) ^ (((row>>2)&7)<<4))
// holds bf16 A[k][row][jg*8+e]. Linear DMA then reproduces the exact LDS image
// that cheb_main's XOR'd ds_read_b128 path expects (R6/R9-verified mapping).
__global__ __launch_bounds__(256) void build_A(
    const float* __restrict__ att, const float* __restrict__ cheb,
    u16* __restrict__ aw)
{
    const int bid = blockIdx.x;
    const int b  = bid & 15;          // b fastest: cheb tile stays L2-hot
    const int it = (bid >> 4) & 15;
    const int jt = bid >> 8;
    const int tid = threadIdx.x;
    const int row = tid >> 2;
    const int jg2 = tid & 3;          // handles jg = jg2*2, jg2*2+1

    const float* ap = att + ((size_t)b * NN + it * 64 + row) * NN + jt * 64 + jg2 * 16;
    f32x4 a0 = *reinterpret_cast<const f32x4*>(ap);
    f32x4 a1 = *reinterpret_cast<const f32x4*>(ap + 4);
    f32x4 a2 = *reinterpret_cast<const f32x4*>(ap + 8);
    f32x4 a3 = *reinterpret_cast<const f32x4*>(ap + 12);

    char* tw = (char*)aw + ((size_t)(b * 16 + it) * 16 + jt) * A_TILE;
    const int key = ((row >> 2) & 7) << 4;

    #pragma unroll
    for (int k = 0; k < KC; ++k) {
        const float* cp = cheb + ((size_t)k * NN + it * 64 + row) * NN + jt * 64 + jg2 * 16;
        f32x4 c0 = *reinterpret_cast<const f32x4*>(cp);
        f32x4 c1 = *reinterpret_cast<const f32x4*>(cp + 4);
        f32x4 c2 = *reinterpret_cast<const f32x4*>(cp + 8);
        f32x4 c3 = *reinterpret_cast<const f32x4*>(cp + 12);
        bf16x8 w0, w1;
        #pragma unroll
        for (int e = 0; e < 4; ++e) {
            w0[e]     = (__bf16)(a0[e] * c0[e]);
            w0[e + 4] = (__bf16)(a1[e] * c1[e]);
            w1[e]     = (__bf16)(a2[e] * c2[e]);
            w1[e + 4] = (__bf16)(a3[e] * c3[e]);
        }
        char* rb = tw + k * 8192 + row * 128;
        *reinterpret_cast<bf16x8*>(rb + (((jg2 * 2) << 4) ^ key))     = w0;
        *reinterpret_cast<bf16x8*>(rb + (((jg2 * 2 + 1) << 4) ^ key)) = w1;
    }
}

// ---------------- tier1 main: 512 thr, 768 blocks, pure DMA+MFMA loop -------
__global__ __launch_bounds__(512, 1) void cheb_main_t1(
    const u16*  __restrict__ yfr,    // y_frags
    const u16*  __restrict__ aw,     // precomputed A (swizzled image)
    const float* __restrict__ Theta, // [K,F,F] f32
    float* __restrict__ out)         // [B,T,N,F] f32
{
    __shared__ __align__(16) char lds[2 * A_TILE + 2 * Y_TILE];   // 114688
    char* Ab0 = lds;
    char* Ab1 = lds + A_TILE;
    char* Yb0 = lds + 2 * A_TILE;
    char* Yb1 = Yb0 + Y_TILE;

    const int tid  = threadIdx.x;
    const int lane = tid & 63;
    const int wid  = tid >> 6;

    // XCD swizzle: 768 % 8 == 0, chunk 96
    const int wg = (blockIdx.x & 7) * 96 + (blockIdx.x >> 3);
    const int b  = wg / 48;
    const int it = (wg % 48) / 3;
    const int tc = wg % 3;
    const int i_base = it * 64;
    const int t_base = tc * 4;

    const int wm  = wid >> 1;   // 0..3 : t in quad
    const int wn  = wid & 1;    // 0..1 : i half
    const int l31 = lane & 31;
    const int lg  = lane >> 5;
    const int sw3 = (l31 >> 2) & 7;

    f32x16 acc[KC][2] = {};
    const int arow = (wn * 32 + l31) * 128;

    const char* aT0 = (const char*)aw + ((size_t)(b * 16 + it) * 16) * A_TILE;

    auto dmaA = [&](char* Ab, int jt) {
        const char* src = aT0 + (size_t)jt * A_TILE;
        #pragma unroll
        for (int q = 0; q < 3; ++q) {
            int seg = wid * 3 + q;                  // 24 segs x 1KB
            load_lds16(src + seg * 1024 + lane * 16, Ab + seg * 1024 + lane * 16);
        }
    };
    auto dmaY = [&](char* Yb, int jt) {
        #pragma unroll
        for (int q = 0; q < 4; ++q) {
            int s    = wid * 4 + q;
            int tile = s >> 3;
            int part = s & 7;
            const u16* gp = yfr + ((size_t)(b * TT + t_base + tile) * 16 + jt) * 4096
                          + (size_t)(part * 64 + lane) * 8;
            load_lds16(gp, Yb + tile * 8192 + part * 1024);
        }
    };

    auto phase4 = [&](const char* Abase, const char* Ybase) {
        const char* yt = Ybase + wm * 8192;
        #pragma unroll
        for (int kk = 0; kk < 4; ++kk) {
            const int off  = ((kk * 2 + lg) ^ sw3) << 4;
            const int yoff = (kk * 2 + lg) * 1024 + l31 * 16;
            bf16x8 af0 = *reinterpret_cast<const bf16x8*>(yt + yoff);
            bf16x8 af1 = *reinterpret_cast<const bf16x8*>(yt + yoff + 512);
            bf16x8 b0 = *reinterpret_cast<const bf16x8*>(Abase + arow + off);
            bf16x8 b1 = *reinterpret_cast<const bf16x8*>(Abase + 8192 + arow + off);
            bf16x8 b2 = *reinterpret_cast<const bf16x8*>(Abase + 16384 + arow + off);
            __builtin_amdgcn_s_setprio(1);
            acc[0][0] = MFMA_B(af0, b0, acc[0][0]); acc[0][1] = MFMA_B(af1, b0, acc[0][1]);
            acc[1][0] = MFMA_B(af0, b1, acc[1][0]); acc[1][1] = MFMA_B(af1, b1, acc[1][1]);
            acc[2][0] = MFMA_B(af0, b2, acc[2][0]); acc[2][1] = MFMA_B(af1, b2, acc[2][1]);
            __builtin_amdgcn_s_setprio(0);
        }
    };

    // prologue: tile 0 in flight, drain, barrier
    dmaA(Ab0, 0);
    dmaY(Yb0, 0);
    asm volatile("s_waitcnt vmcnt(0)" ::: "memory");
    __builtin_amdgcn_s_barrier();

    #pragma unroll 1
    for (int jt = 0; jt < 16; ++jt) {
        char* curA = (jt & 1) ? Ab1 : Ab0;
        char* altA = (jt & 1) ? Ab0 : Ab1;
        char* curY = (jt & 1) ? Yb1 : Yb0;
        char* altY = (jt & 1) ? Yb0 : Yb1;
        if (jt < 15) {
            dmaA(altA, jt + 1);                   // issue early: latency hides
            dmaY(altY, jt + 1);                   // under phase4's MFMA+ds_read
        }
        __builtin_amdgcn_sched_barrier(0);
        phase4(curA, curY);
        asm volatile("s_waitcnt vmcnt(0)" ::: "memory");
        asm volatile("s_waitcnt lgkmcnt(0)" ::: "memory");
        __builtin_amdgcn_s_barrier();
    }

    // ---- stage Theta fragments into A0 region (24 frags * 64 lanes * 16B) ----
    {
        const int fi0 = wid * 3;
        #pragma unroll
        for (int q = 0; q < 3; ++q) {
            int fi = fi0 + q;
            int k  = fi >> 3;
            int mo = (fi >> 2) & 1;
            int s  = fi & 3;
            int o  = 32 * mo + l31;
            int fb = 32 * (s >> 1) + 16 * (s & 1) + 4 * lg;
            bf16x8 v;
            #pragma unroll
            for (int e = 0; e < 8; ++e) {
                int f = fb + (e & 3) + 8 * (e >> 2);
                v[e] = (__bf16)Theta[(k * FF + f) * FF + o];
            }
            *reinterpret_cast<bf16x8*>(lds + (fi * 64 + lane) * 16) = v;
        }
    }
    __syncthreads();

    // ---- epilogue: out[i][o] = sum_{k,f} rhsT[f][i]^T * Theta ----
    f32x16 of[2] = {};
    #pragma unroll
    for (int k = 0; k < KC; ++k) {
        #pragma unroll
        for (int s = 0; s < 4; ++s) {
            bf16x8 pb;
            #pragma unroll
            for (int e = 0; e < 8; ++e)
                pb[e] = (__bf16)acc[k][s >> 1][e + 8 * (s & 1)];
            #pragma unroll
            for (int mo = 0; mo < 2; ++mo) {
                bf16x8 th = *reinterpret_cast<const bf16x8*>(
                    lds + ((((k * 2 + mo) * 4 + s) * 64) + lane) * 16);
                of[mo] = MFMA_B(pb, th, of[mo]);
            }
        }
    }

    const int t = t_base + wm;
    float* op = out + (((size_t)b * TT + t) * NN + i_base + wn * 32) * FF;
    #pragma unroll
    for (int mo = 0; mo < 2; ++mo) {
        #pragma unroll
        for (int r = 0; r < 16; ++r) {
            int row = (r & 3) + 8 * (r >> 2) + 4 * lg;
            int o   = 32 * mo + l31;
            float v = of[mo][r];
            op[(size_t)row * FF + o] = v > 0.0f ? v : 0.0f;
        }
    }
}

// ---------------- tier2 prepass: cheb f32 -> bf16 flat copy (proven) --------
__global__ __launch_bounds__(256) void cheb_to_bf16(
    const float* __restrict__ c, u16* __restrict__ o)
{
    const size_t i = ((size_t)blockIdx.x * 256 + threadIdx.x) * 8;
    f32x4 a = *reinterpret_cast<const f32x4*>(c + i);
    f32x4 b = *reinterpret_cast<const f32x4*>(c + i + 4);
    u16 h[8];
    #pragma unroll
    for (int e = 0; e < 4; ++e) { h[e] = f2bf(a[e]); h[e + 4] = f2bf(b[e]); }
    uint4 w;
    w.x = h[0] | ((unsigned)h[1] << 16);
    w.y = h[2] | ((unsigned)h[3] << 16);
    w.z = h[4] | ((unsigned)h[5] << 16);
    w.w = h[6] | ((unsigned)h[7] << 16);
    *reinterpret_cast<uint4*>(o + i) = w;
}

// ---------------- tier2 main: R9 kernel verbatim (proven 105.9 us) ----------
__global__ __launch_bounds__(512, 1) void cheb_main_t2(
    const u16*  __restrict__ yfr, const float* __restrict__ att,
    const u16*  __restrict__ chb, const float* __restrict__ Theta,
    float* __restrict__ out)
{
    __shared__ __align__(16) char lds[2 * A_TILE + 2 * Y_TILE];
    char* Ab0 = lds;
    char* Ab1 = lds + A_TILE;
    char* Yb0 = lds + 2 * A_TILE;
    char* Yb1 = Yb0 + Y_TILE;

    const int tid  = threadIdx.x;
    const int lane = tid & 63;
    const int wid  = tid >> 6;
    const int wg = (blockIdx.x & 7) * 96 + (blockIdx.x >> 3);
    const int b  = wg / 48;
    const int it = (wg % 48) / 3;
    const int tc = wg % 3;
    const int i_base = it * 64;
    const int t_base = tc * 4;
    const int wm  = wid >> 1;
    const int wn  = wid & 1;
    const int l31 = lane & 31;
    const int lg  = lane >> 5;
    const int sw3 = (l31 >> 2) & 7;
    const int r_a = tid >> 3;
    const int g_a = tid & 7;
    const int swza_st = ((r_a >> 2) & 7) << 4;
    const float* attR = att + ((size_t)b * NN + i_base + r_a) * NN + g_a * 8;
    const u16*   chR  = chb + ((size_t)(i_base + r_a)) * NN + g_a * 8;

    f32x16 acc[KC][2] = {};
    const int arow = (wn * 32 + l31) * 128;
    f32x4 ra0, ra1;
    bf16x8 rc[KC];

    auto LOADS = [&](int j0) {
        ra0 = *reinterpret_cast<const f32x4*>(attR + j0);
        ra1 = *reinterpret_cast<const f32x4*>(attR + j0 + 4);
        #pragma unroll
        for (int k = 0; k < KC; ++k)
            rc[k] = *reinterpret_cast<const bf16x8*>(chR + (size_t)k * NN * NN + j0);
    };
    auto FINISH = [&](char* Ab) {
        #pragma unroll
        for (int k = 0; k < KC; ++k) {
            bf16x8 w;
            #pragma unroll
            for (int e = 0; e < 4; ++e) {
                w[e]     = (__bf16)(ra0[e] * (float)rc[k][e]);
                w[e + 4] = (__bf16)(ra1[e] * (float)rc[k][e + 4]);
            }
            *reinterpret_cast<bf16x8*>(Ab + (k * 64 + r_a) * 128 + ((g_a * 16) ^ swza_st)) = w;
        }
    };
    auto loadY_lds = [&](char* Yb, int jt) {
        #pragma unroll
        for (int q = 0; q < 4; ++q) {
            int s    = wid * 4 + q;
            int tile = s >> 3;
            int part = s & 7;
            const u16* gp = yfr + ((size_t)(b * TT + t_base + tile) * 16 + jt) * 4096
                          + (size_t)(part * 64 + lane) * 8;
            load_lds16(gp, Yb + tile * 8192 + part * 1024);
        }
    };
    auto phase4 = [&](const char* Abase, const char* Ybase) {
        const char* yt = Ybase + wm * 8192;
        #pragma unroll
        for (int kk = 0; kk < 4; ++kk) {
            const int off  = ((kk * 2 + lg) ^ sw3) << 4;
            const int yoff = (kk * 2 + lg) * 1024 + l31 * 16;
            bf16x8 af0 = *reinterpret_cast<const bf16x8*>(yt + yoff);
            bf16x8 af1 = *reinterpret_cast<const bf16x8*>(yt + yoff + 512);
            bf16x8 b0 = *reinterpret_cast<const bf16x8*>(Abase + arow + off);
            bf16x8 b1 = *reinterpret_cast<const bf16x8*>(Abase + 8192 + arow + off);
            bf16x8 b2 = *reinterpret_cast<const bf16x8*>(Abase + 16384 + arow + off);
            __builtin_amdgcn_s_setprio(1);
            acc[0][0] = MFMA_B(af0, b0, acc[0][0]); acc[0][1] = MFMA_B(af1, b0, acc[0][1]);
            acc[1][0] = MFMA_B(af0, b1, acc[1][0]); acc[1][1] = MFMA_B(af1, b1, acc[1][1]);
            acc[2][0] = MFMA_B(af0, b2, acc[2][0]); acc[2][1] = MFMA_B(af1, b2, acc[2][1]);
            __builtin_amdgcn_s_setprio(0);
        }
    };

    auto body = [&](char* curA, char* altA, char* curY, char* altY, int jt) {
        loadY_lds(altY, (jt + 1) & 15);
        __builtin_amdgcn_sched_barrier(0);
        phase4(curA, curY);
        if (jt < 15) {
            FINISH(altA);
            LOADS(((jt + 2) & 15) * 64);
        }
        asm volatile("s_waitcnt vmcnt(5)" ::: "memory");
        asm volatile("s_waitcnt lgkmcnt(0)" ::: "memory");
        __builtin_amdgcn_s_barrier();
    };

    loadY_lds(Yb0, 0);
    LOADS(0);
    asm volatile("s_waitcnt vmcnt(0)" ::: "memory");
    FINISH(Ab0);
    LOADS(64);
    asm volatile("s_waitcnt lgkmcnt(0)" ::: "memory");
    __builtin_amdgcn_s_barrier();

    #pragma unroll 1
    for (int h = 0; h < 8; ++h) {
        body(Ab0, Ab1, Yb0, Yb1, 2 * h);
        body(Ab1, Ab0, Yb1, Yb0, 2 * h + 1);
    }

    {
        const int fi0 = wid * 3;
        #pragma unroll
        for (int q = 0; q < 3; ++q) {
            int fi = fi0 + q;
            int k  = fi >> 3;
            int mo = (fi >> 2) & 1;
            int s  = fi & 3;
            int o  = 32 * mo + l31;
            int fb = 32 * (s >> 1) + 16 * (s & 1) + 4 * lg;
            bf16x8 v;
            #pragma unroll
            for (int e = 0; e < 8; ++e) {
                int f = fb + (e & 3) + 8 * (e >> 2);
                v[e] = (__bf16)Theta[(k * FF + f) * FF + o];
            }
            *reinterpret_cast<bf16x8*>(lds + (fi * 64 + lane) * 16) = v;
        }
    }
    __syncthreads();

    f32x16 of[2] = {};
    #pragma unroll
    for (int k = 0; k < KC; ++k) {
        #pragma unroll
        for (int s = 0; s < 4; ++s) {
            bf16x8 pb;
            #pragma unroll
            for (int e = 0; e < 8; ++e)
                pb[e] = (__bf16)acc[k][s >> 1][e + 8 * (s & 1)];
            #pragma unroll
            for (int mo = 0; mo < 2; ++mo) {
                bf16x8 th = *reinterpret_cast<const bf16x8*>(
                    lds + ((((k * 2 + mo) * 4 + s) * 64) + lane) * 16);
                of[mo] = MFMA_B(pb, th, of[mo]);
            }
        }
    }
    const int t = t_base + wm;
    float* op = out + (((size_t)b * TT + t) * NN + i_base + wn * 32) * FF;
    #pragma unroll
    for (int mo = 0; mo < 2; ++mo) {
        #pragma unroll
        for (int r = 0; r < 16; ++r) {
            int row = (r & 3) + 8 * (r >> 2) + 4 * lg;
            int o   = 32 * mo + l31;
            float v = of[mo][r];
            op[(size_t)row * FF + o] = v > 0.0f ? v : 0.0f;
        }
    }
}

// ---------------- tier3 fallback (no ws): R3 fused kernel -------------------
__global__ __launch_bounds__(512, 2) void cheb_fused(
    const float* __restrict__ x, const float* __restrict__ att,
    const float* __restrict__ cheb, const float* __restrict__ Theta,
    float* __restrict__ out)
{
    __shared__ __align__(16) char lds_raw[2 * (A_TILE + 32768)];
    char* Ab0 = lds_raw;
    char* Xb0 = lds_raw + A_TILE;
    char* Ab1 = lds_raw + A_TILE + 32768;
    char* Xb1 = Ab1 + A_TILE;

    const int tid  = threadIdx.x;
    const int lane = tid & 63;
    const int wid  = tid >> 6;
    const int wg = (blockIdx.x & 7) * 96 + (blockIdx.x >> 3);
    const int b  = wg / 48;
    const int it = (wg % 48) / 3;
    const int tc = wg % 3;
    const int i_base = it * 64;
    const int t_base = tc * 4;
    const int wm  = wid >> 1;
    const int wn  = wid & 1;
    const int l31 = lane & 31;
    const int lg  = lane >> 5;
    const int sw3 = (l31 >> 2) & 7;
    const float* attB = att + (size_t)b * NN * NN;
    const float* xB   = x + (size_t)b * TT * NN * FF;
    const int r_a = tid >> 3;
    const int g_a = tid & 7;
    const int swza_st = ((r_a >> 2) & 7) << 4;
    int tl_s[4], jj_s[4], f_s[4], swzx_st[4];
    #pragma unroll
    for (int s = 0; s < 4; ++s) {
        int u = tid + s * 512;
        tl_s[s] = u >> 9;
        int rem = u & 511;
        jj_s[s] = (rem >> 4) * 2;
        f_s[s]  = (rem & 15) * 4;
        swzx_st[s] = ((f_s[s] >> 2) & 7) << 4;
    }
    f32x4 ra0, ra1, rc0[KC], rc1[KC], rx0[4], rx1[4];
    auto load_tile = [&](int j0) {
        const float* ap = attB + (size_t)(i_base + r_a) * NN + j0 + g_a * 8;
        ra0 = *reinterpret_cast<const f32x4*>(ap);
        ra1 = *reinterpret_cast<const f32x4*>(ap + 4);
        #pragma unroll
        for (int k = 0; k < KC; ++k) {
            const float* cp = cheb + ((size_t)k * NN + i_base + r_a) * NN + j0 + g_a * 8;
            rc0[k] = *reinterpret_cast<const f32x4*>(cp);
            rc1[k] = *reinterpret_cast<const f32x4*>(cp + 4);
        }
        #pragma unroll
        for (int s = 0; s < 4; ++s) {
            const float* xp = xB + ((size_t)(t_base + tl_s[s]) * NN + j0 + jj_s[s]) * FF + f_s[s];
            rx0[s] = *reinterpret_cast<const f32x4*>(xp);
            rx1[s] = *reinterpret_cast<const f32x4*>(xp + FF);
        }
    };
    auto store_A = [&](char* Ab) {
        #pragma unroll
        for (int k = 0; k < KC; ++k) {
            bf16x8 w;
            #pragma unroll
            for (int e = 0; e < 4; ++e) {
                w[e]     = (__bf16)(rc0[k][e] * ra0[e]);
                w[e + 4] = (__bf16)(rc1[k][e] * ra1[e]);
            }
            *reinterpret_cast<bf16x8*>(Ab + (k * 64 + r_a) * 128 + ((g_a * 16) ^ swza_st)) = w;
        }
    };
    auto store_X = [&](char* Xb) {
        #pragma unroll
        for (int s = 0; s < 4; ++s) {
            const int c0 = tl_s[s] * 64 + f_s[s];
            const int coloff = (jj_s[s] * 2) ^ swzx_st[s];
            #pragma unroll
            for (int e = 0; e < 4; ++e) {
                union { __bf16 h[2]; unsigned u32; } pk;
                pk.h[0] = (__bf16)rx0[s][e];
                pk.h[1] = (__bf16)rx1[s][e];
                *reinterpret_cast<unsigned*>(Xb + (c0 + e) * 128 + coloff) = pk.u32;
            }
        }
    };
    f32x16 acc[KC][2] = {};
    const int xrow0 = (wm * 64 + l31) * 128;
    const int xrow1 = xrow0 + 32 * 128;
    const int arow  = (wn * 32 + l31) * 128;
    auto phase = [&](const char* AbR, const char* XbR, int kk) {
        const int off = ((kk * 2 + lg) ^ sw3) << 4;
        bf16x8 af0 = *reinterpret_cast<const bf16x8*>(XbR + xrow0 + off);
        bf16x8 af1 = *reinterpret_cast<const bf16x8*>(XbR + xrow1 + off);
        bf16x8 b0  = *reinterpret_cast<const bf16x8*>(AbR + arow + off);
        bf16x8 b1  = *reinterpret_cast<const bf16x8*>(AbR + 8192 + arow + off);
        bf16x8 b2  = *reinterpret_cast<const bf16x8*>(AbR + 16384 + arow + off);
        __builtin_amdgcn_s_setprio(1);
        acc[0][0] = MFMA_B(af0, b0, acc[0][0]); acc[0][1] = MFMA_B(af1, b0, acc[0][1]);
        acc[1][0] = MFMA_B(af0, b1, acc[1][0]); acc[1][1] = MFMA_B(af1, b1, acc[1][1]);
        acc[2][0] = MFMA_B(af0, b2, acc[2][0]); acc[2][1] = MFMA_B(af1, b2, acc[2][1]);
        __builtin_amdgcn_s_setprio(0);
    };
    load_tile(0);
    store_A(Ab0);
    store_X(Xb0);
    load_tile(64);
    asm volatile("s_waitcnt lgkmcnt(0)" ::: "memory");
    __builtin_amdgcn_s_barrier();
    for (int jt2 = 0; jt2 < 8; ++jt2) {
        const int jt = jt2 * 2;
        phase(Ab0, Xb0, 0);
        phase(Ab0, Xb0, 1);
        store_A(Ab1);
        phase(Ab0, Xb0, 2);
        store_X(Xb1);
        phase(Ab0, Xb0, 3);
        if (jt + 2 < 16) load_tile((jt + 2) * 64);
        asm volatile("s_waitcnt lgkmcnt(0)" ::: "memory");
        __builtin_amdgcn_s_barrier();
        phase(Ab1, Xb1, 0);
        phase(Ab1, Xb1, 1);
        if (jt + 1 < 15) store_A(Ab0);
        phase(Ab1, Xb1, 2);
        if (jt + 1 < 15) store_X(Xb0);
        phase(Ab1, Xb1, 3);
        if (jt + 3 < 16) load_tile((jt + 3) * 64);
        asm volatile("s_waitcnt lgkmcnt(0)" ::: "memory");
        __builtin_amdgcn_s_barrier();
    }
    {
        const int fi0 = wid * 3;
        #pragma unroll
        for (int q = 0; q < 3; ++q) {
            int fi = fi0 + q;
            int k  = fi >> 3;
            int mo = (fi >> 2) & 1;
            int s  = fi & 3;
            int o  = 32 * mo + l31;
            int fb = 32 * (s >> 1) + 16 * (s & 1) + 4 * lg;
            bf16x8 v;
            #pragma unroll
            for (int e = 0; e < 8; ++e) {
                int f = fb + (e & 3) + 8 * (e >> 2);
                v[e] = (__bf16)Theta[(k * FF + f) * FF + o];
            }
            *reinterpret_cast<bf16x8*>(lds_raw + (fi * 64 + lane) * 16) = v;
        }
    }
    __syncthreads();
    f32x16 of[2] = {};
    #pragma unroll
    for (int k = 0; k < KC; ++k) {
        #pragma unroll
        for (int s = 0; s < 4; ++s) {
            bf16x8 pb;
            #pragma unroll
            for (int e = 0; e < 8; ++e)
                pb[e] = (__bf16)acc[k][s >> 1][e + 8 * (s & 1)];
            #pragma unroll
            for (int mo = 0; mo < 2; ++mo) {
                bf16x8 th = *reinterpret_cast<const bf16x8*>(
                    lds_raw + ((((k * 2 + mo) * 4 + s) * 64) + lane) * 16);
                of[mo] = MFMA_B(pb, th, of[mo]);
            }
        }
    }
    const int t = t_base + wm;
    float* op = out + (((size_t)b * TT + t) * NN + i_base + wn * 32) * FF;
    #pragma unroll
    for (int mo = 0; mo < 2; ++mo) {
        #pragma unroll
        for (int r = 0; r < 16; ++r) {
            int row = (r & 3) + 8 * (r >> 2) + 4 * lg;
            int o   = 32 * mo + l31;
            float v = of[mo][r];
            op[(size_t)row * FF + o] = v > 0.0f ? v : 0.0f;
        }
    }
}

extern "C" void kernel_launch(void* const* d_in, const int* in_sizes, int n_in,
                              void* d_out, int out_size, void* d_ws, size_t ws_size,
                              hipStream_t stream) {
    const float* x     = (const float*)d_in[0];
    const float* att   = (const float*)d_in[1];
    const float* cheb  = (const float*)d_in[2];
    const float* Theta = (const float*)d_in[3];
    float* out = (float*)d_out;
    (void)in_sizes; (void)n_in; (void)out_size;

    if (ws_size >= T1_BYTES) {
        u16* yfr = (u16*)d_ws;
        u16* aw  = (u16*)((char*)d_ws + YF_BYTES);
        x_to_yfrags<<<dim3(BB * TT * 16), 256, 0, stream>>>(x, yfr);
        build_A<<<dim3(16 * 16 * 16), 256, 0, stream>>>(att, cheb, aw);
        cheb_main_t1<<<dim3(BB * 16 * 3), 512, 0, stream>>>(yfr, aw, Theta, out);
    } else if (ws_size >= T2_BYTES) {
        u16* yfr = (u16*)d_ws;
        u16* cbf = (u16*)((char*)d_ws + YF_BYTES);
        x_to_yfrags<<<dim3(BB * TT * 16), 256, 0, stream>>>(x, yfr);
        cheb_to_bf16<<<dim3(KC * NN * NN / (256 * 8)), 256, 0, stream>>>(cheb, cbf);
        cheb_main_t2<<<dim3(BB * 16 * 3), 512, 0, stream>>>(yfr, att, cbf, Theta, out);
    } else {
        cheb_fused<<<dim3(BB * 16 * 3), 512, 0, stream>>>(x, att, cheb, Theta, out);
    }
}

// Round 13
// 110.123 us; speedup vs baseline: 1.4356x; 1.4356x over previous
//
#include <hip/hip_runtime.h>
#include <hip/hip_bf16.h>

// B=16, T=12, N=1024, F_IN=F_OUT=64, K=3
#define BB 16
#define TT 12
#define NN 1024
#define FF 64
#define KC 3

typedef __bf16  bf16x8 __attribute__((ext_vector_type(8)));
typedef float   f32x4  __attribute__((ext_vector_type(4)));
typedef float   f32x16 __attribute__((ext_vector_type(16)));
typedef unsigned short u16;

#define A_TILE  24576               // fallback kernel tile (128B rows, XOR)
#define A_ROWB  144                 // hex main: padded A row bytes (0-conflict, R10)
#define A_TILEP (KC * 64 * A_ROWB)  // 27648
#define Y_HEX   (6 * 8192)          // 49152: 6 bt tiles per jt
#define MFMA_B(a, b, c) __builtin_amdgcn_mfma_f32_32x32x16_bf16(a, b, c, 0, 0, 0)

// ws: yfr (25165824) + cheb_bf (6291456) = 31457280
#define YF_BYTES 25165824ull
#define CB_BYTES 6291456ull
#define T2_BYTES (YF_BYTES + CB_BYTES)

static __device__ __forceinline__ u16 f2bf(float v) {
    union { __bf16 b; u16 u; } c; c.b = (__bf16)v; return c.u;
}

static __device__ __forceinline__ void load_lds16(const void* g, void* l) {
    __builtin_amdgcn_global_load_lds(
        (const __attribute__((address_space(1))) unsigned int*)g,
        (__attribute__((address_space(3))) unsigned int*)l, 16, 0, 0);
}

// ---------------- prepass 1: x [B,T,N,F] f32 -> y_frags bf16 (proven) -------
__global__ __launch_bounds__(256) void x_to_yfrags(
    const float* __restrict__ x, u16* __restrict__ y)
{
    __shared__ char tl[64 * 128];
    const int tid = threadIdx.x;
    const int bt  = blockIdx.x >> 4;
    const int jt  = blockIdx.x & 15;
    const int f   = tid & 63;
    const int jr  = tid >> 6;

    const float* xp = x + ((size_t)bt * NN + jt * 64 + jr) * FF + f;
    #pragma unroll
    for (int stp = 0; stp < 16; ++stp) {
        int j = stp * 4 + jr;
        u16 h = f2bf(xp[stp * 4 * FF]);
        *reinterpret_cast<u16*>(tl + j * 128 + ((f * 2) ^ ((j & 7) << 4))) = h;
    }
    __syncthreads();

    u16* yo = y + ((size_t)bt * 16 + jt) * 4096;
    #pragma unroll
    for (int p = 0; p < 2; ++p) {
        int c  = tid + p * 256;
        int s  = c >> 6, fo = c & 63;
        int j0 = (s >> 1) * 16 + (s & 1) * 8;
        u16 h[8];
        #pragma unroll
        for (int e = 0; e < 8; ++e)
            h[e] = *reinterpret_cast<u16*>(tl + (j0 + e) * 128 + ((fo * 2) ^ (e << 4)));
        uint4 w;
        w.x = h[0] | ((unsigned)h[1] << 16);
        w.y = h[2] | ((unsigned)h[3] << 16);
        w.z = h[4] | ((unsigned)h[5] << 16);
        w.w = h[6] | ((unsigned)h[7] << 16);
        *reinterpret_cast<uint4*>(yo + (size_t)c * 8) = w;
    }
}

// ---------------- prepass 2: cheb f32 -> bf16 flat copy (proven) ------------
__global__ __launch_bounds__(256) void cheb_to_bf16(
    const float* __restrict__ c, u16* __restrict__ o)
{
    const size_t i = ((size_t)blockIdx.x * 256 + threadIdx.x) * 8;
    f32x4 a = *reinterpret_cast<const f32x4*>(c + i);
    f32x4 b = *reinterpret_cast<const f32x4*>(c + i + 4);
    u16 h[8];
    #pragma unroll
    for (int e = 0; e < 4; ++e) { h[e] = f2bf(a[e]); h[e + 4] = f2bf(b[e]); }
    uint4 w;
    w.x = h[0] | ((unsigned)h[1] << 16);
    w.y = h[2] | ((unsigned)h[3] << 16);
    w.z = h[4] | ((unsigned)h[5] << 16);
    w.w = h[6] | ((unsigned)h[7] << 16);
    *reinterpret_cast<uint4*>(o + i) = w;
}

// ---------------- hex main: 768 thr (12 waves, 3/SIMD), 512 blocks ----------
// block = (b, i-tile 64, t-hex 6); wave = (t_loc = wid%6, wn = wid/6).
// A staged in-kernel ONCE per 6 t (waves 0-7); y via LDS-DMA; A rows 144B pad.
__global__ __launch_bounds__(768, 3) void cheb_main_hex(
    const u16*  __restrict__ yfr,    // y_frags
    const float* __restrict__ att,   // [B,N,N] f32
    const u16*  __restrict__ chb,    // cheb bf16 [K,N,N]
    const float* __restrict__ Theta, // [K,F,F] f32
    float* __restrict__ out)         // [B,T,N,F] f32
{
    // [A0|A1|Y0|Y1] = 2*27648 + 2*49152 = 153600 B (<= 160 KB)
    __shared__ __align__(16) char lds[2 * A_TILEP + 2 * Y_HEX];
    char* Ab0 = lds;
    char* Ab1 = lds + A_TILEP;
    char* Yb0 = lds + 2 * A_TILEP;
    char* Yb1 = Yb0 + Y_HEX;

    const int tid  = threadIdx.x;
    const int lane = tid & 63;
    const int wid  = tid >> 6;          // 0..11
    const bool staging = (wid < 8);

    // XCD swizzle: 512 blocks % 8 == 0, chunk 64 (= 2 b's per XCD)
    const int wg = (blockIdx.x & 7) * 64 + (blockIdx.x >> 3);
    const int b  = wg >> 5;
    const int rm = wg & 31;
    const int it = rm >> 1;
    const int th = rm & 1;
    const int i_base = it * 64;
    const int t0     = th * 6;

    const int wn    = wid / 6;          // 0..1 : i half
    const int t_loc = wid % 6;          // 0..5 : t within hex
    const int l31 = lane & 31;
    const int lg  = lane >> 5;

    // A-staging map (waves 0-7 only): r_a = tid>>3 (row), g_a = tid&7
    const int r_a = tid >> 3;           // 0..63 for tid<512
    const int g_a = tid & 7;
    const float* attR = att + ((size_t)b * NN + i_base + r_a) * NN + g_a * 8;
    const u16*   chR  = chb + ((size_t)(i_base + r_a)) * NN + g_a * 8;

    f32x16 acc[KC][2] = {};
    const int arow = (wn * 32 + l31) * A_ROWB;

    f32x4 ra0, ra1;     // att (8 f32)
    bf16x8 rc[KC];      // cheb (8 bf16 per k)

    auto LOADS = [&](int j0) {
        ra0 = *reinterpret_cast<const f32x4*>(attR + j0);
        ra1 = *reinterpret_cast<const f32x4*>(attR + j0 + 4);
        #pragma unroll
        for (int k = 0; k < KC; ++k)
            rc[k] = *reinterpret_cast<const bf16x8*>(chR + (size_t)k * NN * NN + j0);
    };
    auto FINISH = [&](char* Ab) {
        #pragma unroll
        for (int k = 0; k < KC; ++k) {
            bf16x8 w;
            #pragma unroll
            for (int e = 0; e < 4; ++e) {
                w[e]     = (__bf16)(ra0[e] * (float)rc[k][e]);
                w[e + 4] = (__bf16)(ra1[e] * (float)rc[k][e + 4]);
            }
            *reinterpret_cast<bf16x8*>(Ab + (k * 64 + r_a) * A_ROWB + g_a * 16) = w;
        }
    };
    // y DMA: 6 tiles x 8 KB = 48 segs of 1KB; 12 waves x 4 segs
    auto dmaY = [&](char* Yb, int jt) {
        #pragma unroll
        for (int q = 0; q < 4; ++q) {
            int s    = wid * 4 + q;
            int tile = s >> 3;          // bt local 0..5
            int part = s & 7;
            const u16* gp = yfr + ((size_t)(b * TT + t0 + tile) * 16 + jt) * 4096
                          + (size_t)(part * 64 + lane) * 8;
            load_lds16(gp, Yb + tile * 8192 + part * 1024);
        }
    };

    auto phase4 = [&](const char* Abase, const char* Ybase) {
        const char* yt = Ybase + t_loc * 8192;
        #pragma unroll
        for (int kk = 0; kk < 4; ++kk) {
            const int off  = (kk * 2 + lg) * 16;
            const int yoff = (kk * 2 + lg) * 1024 + l31 * 16;
            bf16x8 af0 = *reinterpret_cast<const bf16x8*>(yt + yoff);
            bf16x8 af1 = *reinterpret_cast<const bf16x8*>(yt + yoff + 512);
            bf16x8 b0 = *reinterpret_cast<const bf16x8*>(Abase + arow + off);
            bf16x8 b1 = *reinterpret_cast<const bf16x8*>(Abase + 64 * A_ROWB + arow + off);
            bf16x8 b2 = *reinterpret_cast<const bf16x8*>(Abase + 128 * A_ROWB + arow + off);
            __builtin_amdgcn_s_setprio(1);
            acc[0][0] = MFMA_B(af0, b0, acc[0][0]); acc[0][1] = MFMA_B(af1, b0, acc[0][1]);
            acc[1][0] = MFMA_B(af0, b1, acc[1][0]); acc[1][1] = MFMA_B(af1, b1, acc[1][1]);
            acc[2][0] = MFMA_B(af0, b2, acc[2][0]); acc[2][1] = MFMA_B(af1, b2, acc[2][1]);
            __builtin_amdgcn_s_setprio(0);
        }
    };

    // prologue: A[0] staged; att/cheb(1) + y(0) in flight
    if (staging) {
        LOADS(0);
    }
    dmaY(Yb0, 0);
    if (staging) {
        FINISH(Ab0);               // compiler waits the 5 LOADS(0)
        LOADS(64);                 // 5 loads in flight across barrier
        asm volatile("s_waitcnt vmcnt(5)" ::: "memory");   // drain dmaY(0) only
    } else {
        asm volatile("s_waitcnt vmcnt(0)" ::: "memory");
    }
    asm volatile("s_waitcnt lgkmcnt(0)" ::: "memory");
    __builtin_amdgcn_s_barrier();

    // body: issue y(jt+1); stage A(jt+1); issue att/cheb(jt+2); compute jt;
    // counted vmcnt leaves the 5 att/cheb loads in flight across the barrier.
    // All issues unconditional (&15 wrap) so the outstanding count is uniform.
    #pragma unroll 1
    for (int jt = 0; jt < 16; ++jt) {
        char* curA = (jt & 1) ? Ab1 : Ab0;
        char* altA = (jt & 1) ? Ab0 : Ab1;
        char* curY = (jt & 1) ? Yb1 : Yb0;
        char* altY = (jt & 1) ? Yb0 : Yb1;
        dmaY(altY, (jt + 1) & 15);                 // 4 vmem
        if (staging) {
            FINISH(altA);                          // waits att/cheb(jt+1)
            LOADS(((jt + 2) & 15) * 64);           // 5 vmem (newest)
        }
        __builtin_amdgcn_sched_barrier(0);
        phase4(curA, curY);
        if (staging) {
            asm volatile("s_waitcnt vmcnt(5)" ::: "memory");   // dmaY done, LOADS in flight
        } else {
            asm volatile("s_waitcnt vmcnt(0)" ::: "memory");   // its 4 dmaY done
        }
        asm volatile("s_waitcnt lgkmcnt(0)" ::: "memory");
        __builtin_amdgcn_s_barrier();
    }

    // ---- stage Theta fragments into A0 region (24 frags * 64 lanes * 16B) ----
    {
        const int fi0 = wid * 2;
        #pragma unroll
        for (int q = 0; q < 2; ++q) {
            int fi = fi0 + q;
            int k  = fi >> 3;
            int mo = (fi >> 2) & 1;
            int s  = fi & 3;
            int o  = 32 * mo + l31;
            int fb = 32 * (s >> 1) + 16 * (s & 1) + 4 * lg;
            bf16x8 v;
            #pragma unroll
            for (int e = 0; e < 8; ++e) {
                int f = fb + (e & 3) + 8 * (e >> 2);
                v[e] = (__bf16)Theta[(k * FF + f) * FF + o];
            }
            *reinterpret_cast<bf16x8*>(lds + (fi * 64 + lane) * 16) = v;
        }
    }
    __syncthreads();

    // ---- epilogue: out[i][o] = sum_{k,f} rhsT[f][i]^T * Theta ----
    f32x16 of[2] = {};
    #pragma unroll
    for (int k = 0; k < KC; ++k) {
        #pragma unroll
        for (int s = 0; s < 4; ++s) {
            bf16x8 pb;
            #pragma unroll
            for (int e = 0; e < 8; ++e)
                pb[e] = (__bf16)acc[k][s >> 1][e + 8 * (s & 1)];
            #pragma unroll
            for (int mo = 0; mo < 2; ++mo) {
                bf16x8 th = *reinterpret_cast<const bf16x8*>(
                    lds + ((((k * 2 + mo) * 4 + s) * 64) + lane) * 16);
                of[mo] = MFMA_B(pb, th, of[mo]);
            }
        }
    }

    const int t = t0 + t_loc;
    float* op = out + (((size_t)b * TT + t) * NN + i_base + wn * 32) * FF;
    #pragma unroll
    for (int mo = 0; mo < 2; ++mo) {
        #pragma unroll
        for (int r = 0; r < 16; ++r) {
            int row = (r & 3) + 8 * (r >> 2) + 4 * lg;
            int o   = 32 * mo + l31;
            float v = of[mo][r];
            op[(size_t)row * FF + o] = v > 0.0f ? v : 0.0f;
        }
    }
}

// ---------------- fallback (no ws): R3 fused kernel -------------------------
__global__ __launch_bounds__(512, 2) void cheb_fused(
    const float* __restrict__ x, const float* __restrict__ att,
    const float* __restrict__ cheb, const float* __restrict__ Theta,
    float* __restrict__ out)
{
    __shared__ __align__(16) char lds_raw[2 * (A_TILE + 32768)];
    char* Ab0 = lds_raw;
    char* Xb0 = lds_raw + A_TILE;
    char* Ab1 = lds_raw + A_TILE + 32768;
    char* Xb1 = Ab1 + A_TILE;

    const int tid  = threadIdx.x;
    const int lane = tid & 63;
    const int wid  = tid >> 6;
    const int wg = (blockIdx.x & 7) * 96 + (blockIdx.x >> 3);
    const int b  = wg / 48;
    const int it = (wg % 48) / 3;
    const int tc = wg % 3;
    const int i_base = it * 64;
    const int t_base = tc * 4;
    const int wm  = wid >> 1;
    const int wn  = wid & 1;
    const int l31 = lane & 31;
    const int lg  = lane >> 5;
    const int sw3 = (l31 >> 2) & 7;
    const float* attB = att + (size_t)b * NN * NN;
    const float* xB   = x + (size_t)b * TT * NN * FF;
    const int r_a = tid >> 3;
    const int g_a = tid & 7;
    const int swza_st = ((r_a >> 2) & 7) << 4;
    int tl_s[4], jj_s[4], f_s[4], swzx_st[4];
    #pragma unroll
    for (int s = 0; s < 4; ++s) {
        int u = tid + s * 512;
        tl_s[s] = u >> 9;
        int rem = u & 511;
        jj_s[s] = (rem >> 4) * 2;
        f_s[s]  = (rem & 15) * 4;
        swzx_st[s] = ((f_s[s] >> 2) & 7) << 4;
    }
    f32x4 ra0, ra1, rc0[KC], rc1[KC], rx0[4], rx1[4];
    auto load_tile = [&](int j0) {
        const float* ap = attB + (size_t)(i_base + r_a) * NN + j0 + g_a * 8;
        ra0 = *reinterpret_cast<const f32x4*>(ap);
        ra1 = *reinterpret_cast<const f32x4*>(ap + 4);
        #pragma unroll
        for (int k = 0; k < KC; ++k) {
            const float* cp = cheb + ((size_t)k * NN + i_base + r_a) * NN + j0 + g_a * 8;
            rc0[k] = *reinterpret_cast<const f32x4*>(cp);
            rc1[k] = *reinterpret_cast<const f32x4*>(cp + 4);
        }
        #pragma unroll
        for (int s = 0; s < 4; ++s) {
            const float* xp = xB + ((size_t)(t_base + tl_s[s]) * NN + j0 + jj_s[s]) * FF + f_s[s];
            rx0[s] = *reinterpret_cast<const f32x4*>(xp);
            rx1[s] = *reinterpret_cast<const f32x4*>(xp + FF);
        }
    };
    auto store_A = [&](char* Ab) {
        #pragma unroll
        for (int k = 0; k < KC; ++k) {
            bf16x8 w;
            #pragma unroll
            for (int e = 0; e < 4; ++e) {
                w[e]     = (__bf16)(rc0[k][e] * ra0[e]);
                w[e + 4] = (__bf16)(rc1[k][e] * ra1[e]);
            }
            *reinterpret_cast<bf16x8*>(Ab + (k * 64 + r_a) * 128 + ((g_a * 16) ^ swza_st)) = w;
        }
    };
    auto store_X = [&](char* Xb) {
        #pragma unroll
        for (int s = 0; s < 4; ++s) {
            const int c0 = tl_s[s] * 64 + f_s[s];
            const int coloff = (jj_s[s] * 2) ^ swzx_st[s];
            #pragma unroll
            for (int e = 0; e < 4; ++e) {
                union { __bf16 h[2]; unsigned u32; } pk;
                pk.h[0] = (__bf16)rx0[s][e];
                pk.h[1] = (__bf16)rx1[s][e];
                *reinterpret_cast<unsigned*>(Xb + (c0 + e) * 128 + coloff) = pk.u32;
            }
        }
    };
    f32x16 acc[KC][2] = {};
    const int xrow0 = (wm * 64 + l31) * 128;
    const int xrow1 = xrow0 + 32 * 128;
    const int arow  = (wn * 32 + l31) * 128;
    auto phase = [&](const char* AbR, const char* XbR, int kk) {
        const int off = ((kk * 2 + lg) ^ sw3) << 4;
        bf16x8 af0 = *reinterpret_cast<const bf16x8*>(XbR + xrow0 + off);
        bf16x8 af1 = *reinterpret_cast<const bf16x8*>(XbR + xrow1 + off);
        bf16x8 b0  = *reinterpret_cast<const bf16x8*>(AbR + arow + off);
        bf16x8 b1  = *reinterpret_cast<const bf16x8*>(AbR + 8192 + arow + off);
        bf16x8 b2  = *reinterpret_cast<const bf16x8*>(AbR + 16384 + arow + off);
        __builtin_amdgcn_s_setprio(1);
        acc[0][0] = MFMA_B(af0, b0, acc[0][0]); acc[0][1] = MFMA_B(af1, b0, acc[0][1]);
        acc[1][0] = MFMA_B(af0, b1, acc[1][0]); acc[1][1] = MFMA_B(af1, b1, acc[1][1]);
        acc[2][0] = MFMA_B(af0, b2, acc[2][0]); acc[2][1] = MFMA_B(af1, b2, acc[2][1]);
        __builtin_amdgcn_s_setprio(0);
    };
    load_tile(0);
    store_A(Ab0);
    store_X(Xb0);
    load_tile(64);
    asm volatile("s_waitcnt lgkmcnt(0)" ::: "memory");
    __builtin_amdgcn_s_barrier();
    for (int jt2 = 0; jt2 < 8; ++jt2) {
        const int jt = jt2 * 2;
        phase(Ab0, Xb0, 0);
        phase(Ab0, Xb0, 1);
        store_A(Ab1);
        phase(Ab0, Xb0, 2);
        store_X(Xb1);
        phase(Ab0, Xb0, 3);
        if (jt + 2 < 16) load_tile((jt + 2) * 64);
        asm volatile("s_waitcnt lgkmcnt(0)" ::: "memory");
        __builtin_amdgcn_s_barrier();
        phase(Ab1, Xb1, 0);
        phase(Ab1, Xb1, 1);
        if (jt + 1 < 15) store_A(Ab0);
        phase(Ab1, Xb1, 2);
        if (jt + 1 < 15) store_X(Xb0);
        phase(Ab1, Xb1, 3);
        if (jt + 3 < 16) load_tile((jt + 3) * 64);
        asm volatile("s_waitcnt lgkmcnt(0)" ::: "memory");
        __builtin_amdgcn_s_barrier();
    }
    {
        const int fi0 = wid * 3;
        #pragma unroll
        for (int q = 0; q < 3; ++q) {
            int fi = fi0 + q;
            int k  = fi >> 3;
            int mo = (fi >> 2) & 1;
            int s  = fi & 3;
            int o  = 32 * mo + l31;
            int fb = 32 * (s >> 1) + 16 * (s & 1) + 4 * lg;
            bf16x8 v;
            #pragma unroll
            for (int e = 0; e < 8; ++e) {
                int f = fb + (e & 3) + 8 * (e >> 2);
                v[e] = (__bf16)Theta[(k * FF + f) * FF + o];
            }
            *reinterpret_cast<bf16x8*>(lds_raw + (fi * 64 + lane) * 16) = v;
        }
    }
    __syncthreads();
    f32x16 of[2] = {};
    #pragma unroll
    for (int k = 0; k < KC; ++k) {
        #pragma unroll
        for (int s = 0; s < 4; ++s) {
            bf16x8 pb;
            #pragma unroll
            for (int e = 0; e < 8; ++e)
                pb[e] = (__bf16)acc[k][s >> 1][e + 8 * (s & 1)];
            #pragma unroll
            for (int mo = 0; mo < 2; ++mo) {
                bf16x8 th = *reinterpret_cast<const bf16x8*>(
                    lds_raw + ((((k * 2 + mo) * 4 + s) * 64) + lane) * 16);
                of[mo] = MFMA_B(pb, th, of[mo]);
            }
        }
    }
    const int t = t_base + wm;
    float* op = out + (((size_t)b * TT + t) * NN + i_base + wn * 32) * FF;
    #pragma unroll
    for (int mo = 0; mo < 2; ++mo) {
        #pragma unroll
        for (int r = 0; r < 16; ++r) {
            int row = (r & 3) + 8 * (r >> 2) + 4 * lg;
            int o   = 32 * mo + l31;
            float v = of[mo][r];
            op[(size_t)row * FF + o] = v > 0.0f ? v : 0.0f;
        }
    }
}

extern "C" void kernel_launch(void* const* d_in, const int* in_sizes, int n_in,
                              void* d_out, int out_size, void* d_ws, size_t ws_size,
                              hipStream_t stream) {
    const float* x     = (const float*)d_in[0];
    const float* att   = (const float*)d_in[1];
    const float* cheb  = (const float*)d_in[2];
    const float* Theta = (const float*)d_in[3];
    float* out = (float*)d_out;
    (void)in_sizes; (void)n_in; (void)out_size;

    if (ws_size >= T2_BYTES) {
        u16* yfr = (u16*)d_ws;
        u16* cbf = (u16*)((char*)d_ws + YF_BYTES);
        x_to_yfrags<<<dim3(BB * TT * 16), 256, 0, stream>>>(x, yfr);
        cheb_to_bf16<<<dim3(KC * NN * NN / (256 * 8)), 256, 0, stream>>>(cheb, cbf);
        cheb_main_hex<<<dim3(BB * 16 * 2), 768, 0, stream>>>(yfr, att, cbf, Theta, out);
    } else {
        cheb_fused<<<dim3(BB * 16 * 3), 512, 0, stream>>>(x, att, cheb, Theta, out);
    }
}

// Round 15
// 107.960 us; speedup vs baseline: 1.4644x; 1.0200x over previous
//
#include <hip/hip_runtime.h>
#include <hip/hip_bf16.h>

// B=16, T=12, N=1024, F_IN=F_OUT=64, K=3
#define BB 16
#define TT 12
#define NN 1024
#define FF 64
#define KC 3

typedef __bf16  bf16x8 __attribute__((ext_vector_type(8)));
typedef float   f32x4  __attribute__((ext_vector_type(4)));
typedef float   f32x16 __attribute__((ext_vector_type(16)));
typedef unsigned short u16;

#define A_TILE  24576               // fallback tile (128B rows, XOR)
#define A_ROWB  144                 // main: padded A rows, 0-conflict (R10/R13)
#define A_TILEP (KC * 64 * A_ROWB)  // 27648
#define Y_TILE  32768               // 4 bt * 8KB per jt
#define MFMA_B(a, b, c) __builtin_amdgcn_mfma_f32_32x32x16_bf16(a, b, c, 0, 0, 0)

// ws: yfr (25165824) + cheb_bf (6291456) = 31457280
#define YF_BYTES 25165824ull
#define CB_BYTES 6291456ull
#define T2_BYTES (YF_BYTES + CB_BYTES)

static __device__ __forceinline__ u16 f2bf(float v) {
    union { __bf16 b; u16 u; } c; c.b = (__bf16)v; return c.u;
}

static __device__ __forceinline__ void load_lds16(const void* g, void* l) {
    __builtin_amdgcn_global_load_lds(
        (const __attribute__((address_space(1))) unsigned int*)g,
        (__attribute__((address_space(3))) unsigned int*)l, 16, 0, 0);
}

// ---------------- prepass 1: x [B,T,N,F] f32 -> y_frags bf16 (proven) -------
__global__ __launch_bounds__(256) void x_to_yfrags(
    const float* __restrict__ x, u16* __restrict__ y)
{
    __shared__ char tl[64 * 128];
    const int tid = threadIdx.x;
    const int bt  = blockIdx.x >> 4;
    const int jt  = blockIdx.x & 15;
    const int f   = tid & 63;
    const int jr  = tid >> 6;

    const float* xp = x + ((size_t)bt * NN + jt * 64 + jr) * FF + f;
    #pragma unroll
    for (int stp = 0; stp < 16; ++stp) {
        int j = stp * 4 + jr;
        u16 h = f2bf(xp[stp * 4 * FF]);
        *reinterpret_cast<u16*>(tl + j * 128 + ((f * 2) ^ ((j & 7) << 4))) = h;
    }
    __syncthreads();

    u16* yo = y + ((size_t)bt * 16 + jt) * 4096;
    #pragma unroll
    for (int p = 0; p < 2; ++p) {
        int c  = tid + p * 256;
        int s  = c >> 6, fo = c & 63;
        int j0 = (s >> 1) * 16 + (s & 1) * 8;
        u16 h[8];
        #pragma unroll
        for (int e = 0; e < 8; ++e)
            h[e] = *reinterpret_cast<u16*>(tl + (j0 + e) * 128 + ((fo * 2) ^ (e << 4)));
        uint4 w;
        w.x = h[0] | ((unsigned)h[1] << 16);
        w.y = h[2] | ((unsigned)h[3] << 16);
        w.z = h[4] | ((unsigned)h[5] << 16);
        w.w = h[6] | ((unsigned)h[7] << 16);
        *reinterpret_cast<uint4*>(yo + (size_t)c * 8) = w;
    }
}

// ---------------- prepass 2: cheb f32 -> bf16 flat copy (proven) ------------
__global__ __launch_bounds__(256) void cheb_to_bf16(
    const float* __restrict__ c, u16* __restrict__ o)
{
    const size_t i = ((size_t)blockIdx.x * 256 + threadIdx.x) * 8;
    f32x4 a = *reinterpret_cast<const f32x4*>(c + i);
    f32x4 b = *reinterpret_cast<const f32x4*>(c + i + 4);
    u16 h[8];
    #pragma unroll
    for (int e = 0; e < 4; ++e) { h[e] = f2bf(a[e]); h[e + 4] = f2bf(b[e]); }
    uint4 w;
    w.x = h[0] | ((unsigned)h[1] << 16);
    w.y = h[2] | ((unsigned)h[3] << 16);
    w.z = h[4] | ((unsigned)h[5] << 16);
    w.w = h[6] | ((unsigned)h[7] << 16);
    *reinterpret_cast<uint4*>(o + i) = w;
}

// ---------------- main: 512 thr (8 waves), 768 blocks -----------------------
// R9 base + y TRIPLE buffer issued 2 jt ahead + 144B-pad A (0 conflicts).
// LDS pointers kept as byte OFFSETS (hipcc rejects LDS-pointer arrays).
__global__ __launch_bounds__(512, 1) void cheb_main_t2(
    const u16*  __restrict__ yfr,    // y_frags
    const float* __restrict__ att,   // [B,N,N] f32
    const u16*  __restrict__ chb,    // cheb bf16 [K,N,N]
    const float* __restrict__ Theta, // [K,F,F] f32
    float* __restrict__ out)         // [B,T,N,F] f32
{
    // [A0|A1|Y0|Y1|Y2] = 2*27648 + 3*32768 = 153600 B
    __shared__ __align__(16) char lds[2 * A_TILEP + 3 * Y_TILE];

    const int tid  = threadIdx.x;
    const int lane = tid & 63;
    const int wid  = tid >> 6;

    // XCD swizzle: 768 % 8 == 0, chunk 96
    const int wg = (blockIdx.x & 7) * 96 + (blockIdx.x >> 3);
    const int b  = wg / 48;
    const int it = (wg % 48) / 3;
    const int tc = wg % 3;
    const int i_base = it * 64;
    const int t_base = tc * 4;

    const int wm  = wid >> 1;   // 0..3 : t in quad
    const int wn  = wid & 1;    // 0..1 : i half
    const int l31 = lane & 31;
    const int lg  = lane >> 5;

    // A-staging map: r_a = tid>>3 (row), g_a = tid&7 (8-j group)
    const int r_a = tid >> 3;
    const int g_a = tid & 7;
    const float* attR = att + ((size_t)b * NN + i_base + r_a) * NN + g_a * 8;
    const u16*   chR  = chb + ((size_t)(i_base + r_a)) * NN + g_a * 8;

    f32x16 acc[KC][2] = {};
    const int arow = (wn * 32 + l31) * A_ROWB;

    f32x4 ra0, ra1;     // att (8 f32)
    bf16x8 rc[KC];      // cheb (8 bf16 per k)

    auto LOADS = [&](int j0) {
        ra0 = *reinterpret_cast<const f32x4*>(attR + j0);
        ra1 = *reinterpret_cast<const f32x4*>(attR + j0 + 4);
        #pragma unroll
        for (int k = 0; k < KC; ++k)
            rc[k] = *reinterpret_cast<const bf16x8*>(chR + (size_t)k * NN * NN + j0);
    };
    auto FINISH = [&](int aOff) {
        #pragma unroll
        for (int k = 0; k < KC; ++k) {
            bf16x8 w;
            #pragma unroll
            for (int e = 0; e < 4; ++e) {
                w[e]     = (__bf16)(ra0[e] * (float)rc[k][e]);
                w[e + 4] = (__bf16)(ra1[e] * (float)rc[k][e + 4]);
            }
            *reinterpret_cast<bf16x8*>(lds + aOff + (k * 64 + r_a) * A_ROWB + g_a * 16) = w;
        }
    };
    auto dmaY = [&](int yOff, int jt) {
        #pragma unroll
        for (int q = 0; q < 4; ++q) {
            int s    = wid * 4 + q;
            int tile = s >> 3;
            int part = s & 7;
            const u16* gp = yfr + ((size_t)(b * TT + t_base + tile) * 16 + jt) * 4096
                          + (size_t)(part * 64 + lane) * 8;
            load_lds16(gp, lds + yOff + tile * 8192 + part * 1024);
        }
    };

    auto phase4 = [&](int aOff, int yOff) {
        const char* yt = lds + yOff + wm * 8192;
        const char* ab = lds + aOff;
        #pragma unroll
        for (int kk = 0; kk < 4; ++kk) {
            const int off  = (kk * 2 + lg) * 16;
            const int yoff = (kk * 2 + lg) * 1024 + l31 * 16;
            bf16x8 af0 = *reinterpret_cast<const bf16x8*>(yt + yoff);
            bf16x8 af1 = *reinterpret_cast<const bf16x8*>(yt + yoff + 512);
            bf16x8 b0 = *reinterpret_cast<const bf16x8*>(ab + arow + off);
            bf16x8 b1 = *reinterpret_cast<const bf16x8*>(ab + 64 * A_ROWB + arow + off);
            bf16x8 b2 = *reinterpret_cast<const bf16x8*>(ab + 128 * A_ROWB + arow + off);
            __builtin_amdgcn_s_setprio(1);
            acc[0][0] = MFMA_B(af0, b0, acc[0][0]); acc[0][1] = MFMA_B(af1, b0, acc[0][1]);
            acc[1][0] = MFMA_B(af0, b1, acc[1][0]); acc[1][1] = MFMA_B(af1, b1, acc[1][1]);
            acc[2][0] = MFMA_B(af0, b2, acc[2][0]); acc[2][1] = MFMA_B(af1, b2, acc[2][1]);
            __builtin_amdgcn_s_setprio(0);
        }
    };

    // prologue: y(0),y(1) + att/cheb(0),(1) in flight; stage A[0]
    dmaY(2 * A_TILEP, 0);            // Y0: 4
    LOADS(0);                        // 5
    dmaY(2 * A_TILEP + Y_TILE, 1);   // Y1: 4
    FINISH(0);                       // compiler vmcnt wait: y(0)+ac(0) done
    LOADS(64);                       // 5 -> steady-state 9 outstanding
    asm volatile("s_waitcnt lgkmcnt(0)" ::: "memory");
    __builtin_amdgcn_s_barrier();

    // body jt: issue y(jt+2); compute jt; stage A[jt+1]; issue ac(jt+2);
    // vmcnt(9) = {ac(jt+2) 5 + y(jt+2) 4} in flight, everything older done.
    #pragma unroll 1
    for (int jt = 0; jt < 16; ++jt) {
        const int curA = (jt & 1) * A_TILEP;
        const int altA = ((jt & 1) ^ 1) * A_TILEP;
        const int curY = 2 * A_TILEP + (jt % 3) * Y_TILE;
        const int nxtY = 2 * A_TILEP + ((jt + 2) % 3) * Y_TILE;
        dmaY(nxtY, (jt + 2) & 15);                 // 2-ahead
        __builtin_amdgcn_sched_barrier(0);
        phase4(curA, curY);
        FINISH(altA);                              // auto vmcnt after ~2k cyc of MFMA
        LOADS(((jt + 2) & 15) * 64);
        asm volatile("s_waitcnt vmcnt(9)" ::: "memory");
        asm volatile("s_waitcnt lgkmcnt(0)" ::: "memory");
        __builtin_amdgcn_s_barrier();
    }

    // ---- stage Theta fragments into A region (24 frags * 64 lanes * 16B) ----
    {
        const int fi0 = wid * 3;
        #pragma unroll
        for (int q = 0; q < 3; ++q) {
            int fi = fi0 + q;
            int k  = fi >> 3;
            int mo = (fi >> 2) & 1;
            int s  = fi & 3;
            int o  = 32 * mo + l31;
            int fb = 32 * (s >> 1) + 16 * (s & 1) + 4 * lg;
            bf16x8 v;
            #pragma unroll
            for (int e = 0; e < 8; ++e) {
                int f = fb + (e & 3) + 8 * (e >> 2);
                v[e] = (__bf16)Theta[(k * FF + f) * FF + o];
            }
            *reinterpret_cast<bf16x8*>(lds + (fi * 64 + lane) * 16) = v;
        }
    }
    __syncthreads();

    // ---- epilogue: out[i][o] = sum_{k,f} rhsT[f][i]^T * Theta ----
    f32x16 of[2] = {};
    #pragma unroll
    for (int k = 0; k < KC; ++k) {
        #pragma unroll
        for (int s = 0; s < 4; ++s) {
            bf16x8 pb;
            #pragma unroll
            for (int e = 0; e < 8; ++e)
                pb[e] = (__bf16)acc[k][s >> 1][e + 8 * (s & 1)];
            #pragma unroll
            for (int mo = 0; mo < 2; ++mo) {
                bf16x8 th = *reinterpret_cast<const bf16x8*>(
                    lds + ((((k * 2 + mo) * 4 + s) * 64) + lane) * 16);
                of[mo] = MFMA_B(pb, th, of[mo]);
            }
        }
    }
    const int t = t_base + wm;
    float* op = out + (((size_t)b * TT + t) * NN + i_base + wn * 32) * FF;
    #pragma unroll
    for (int mo = 0; mo < 2; ++mo) {
        #pragma unroll
        for (int r = 0; r < 16; ++r) {
            int row = (r & 3) + 8 * (r >> 2) + 4 * lg;
            int o   = 32 * mo + l31;
            float v = of[mo][r];
            op[(size_t)row * FF + o] = v > 0.0f ? v : 0.0f;
        }
    }
}

// ---------------- fallback (no ws): R3 fused kernel -------------------------
__global__ __launch_bounds__(512, 2) void cheb_fused(
    const float* __restrict__ x, const float* __restrict__ att,
    const float* __restrict__ cheb, const float* __restrict__ Theta,
    float* __restrict__ out)
{
    __shared__ __align__(16) char lds_raw[2 * (A_TILE + 32768)];
    char* Ab0 = lds_raw;
    char* Xb0 = lds_raw + A_TILE;
    char* Ab1 = lds_raw + A_TILE + 32768;
    char* Xb1 = Ab1 + A_TILE;

    const int tid  = threadIdx.x;
    const int lane = tid & 63;
    const int wid  = tid >> 6;
    const int wg = (blockIdx.x & 7) * 96 + (blockIdx.x >> 3);
    const int b  = wg / 48;
    const int it = (wg % 48) / 3;
    const int tc = wg % 3;
    const int i_base = it * 64;
    const int t_base = tc * 4;
    const int wm  = wid >> 1;
    const int wn  = wid & 1;
    const int l31 = lane & 31;
    const int lg  = lane >> 5;
    const int sw3 = (l31 >> 2) & 7;
    const float* attB = att + (size_t)b * NN * NN;
    const float* xB   = x + (size_t)b * TT * NN * FF;
    const int r_a = tid >> 3;
    const int g_a = tid & 7;
    const int swza_st = ((r_a >> 2) & 7) << 4;
    int tl_s[4], jj_s[4], f_s[4], swzx_st[4];
    #pragma unroll
    for (int s = 0; s < 4; ++s) {
        int u = tid + s * 512;
        tl_s[s] = u >> 9;
        int rem = u & 511;
        jj_s[s] = (rem >> 4) * 2;
        f_s[s]  = (rem & 15) * 4;
        swzx_st[s] = ((f_s[s] >> 2) & 7) << 4;
    }
    f32x4 ra0, ra1, rc0[KC], rc1[KC], rx0[4], rx1[4];
    auto load_tile = [&](int j0) {
        const float* ap = attB + (size_t)(i_base + r_a) * NN + j0 + g_a * 8;
        ra0 = *reinterpret_cast<const f32x4*>(ap);
        ra1 = *reinterpret_cast<const f32x4*>(ap + 4);
        #pragma unroll
        for (int k = 0; k < KC; ++k) {
            const float* cp = cheb + ((size_t)k * NN + i_base + r_a) * NN + j0 + g_a * 8;
            rc0[k] = *reinterpret_cast<const f32x4*>(cp);
            rc1[k] = *reinterpret_cast<const f32x4*>(cp + 4);
        }
        #pragma unroll
        for (int s = 0; s < 4; ++s) {
            const float* xp = xB + ((size_t)(t_base + tl_s[s]) * NN + j0 + jj_s[s]) * FF + f_s[s];
            rx0[s] = *reinterpret_cast<const f32x4*>(xp);
            rx1[s] = *reinterpret_cast<const f32x4*>(xp + FF);
        }
    };
    auto store_A = [&](char* Ab) {
        #pragma unroll
        for (int k = 0; k < KC; ++k) {
            bf16x8 w;
            #pragma unroll
            for (int e = 0; e < 4; ++e) {
                w[e]     = (__bf16)(rc0[k][e] * ra0[e]);
                w[e + 4] = (__bf16)(rc1[k][e] * ra1[e]);
            }
            *reinterpret_cast<bf16x8*>(Ab + (k * 64 + r_a) * 128 + ((g_a * 16) ^ swza_st)) = w;
        }
    };
    auto store_X = [&](char* Xb) {
        #pragma unroll
        for (int s = 0; s < 4; ++s) {
            const int c0 = tl_s[s] * 64 + f_s[s];
            const int coloff = (jj_s[s] * 2) ^ swzx_st[s];
            #pragma unroll
            for (int e = 0; e < 4; ++e) {
                union { __bf16 h[2]; unsigned u32; } pk;
                pk.h[0] = (__bf16)rx0[s][e];
                pk.h[1] = (__bf16)rx1[s][e];
                *reinterpret_cast<unsigned*>(Xb + (c0 + e) * 128 + coloff) = pk.u32;
            }
        }
    };
    f32x16 acc[KC][2] = {};
    const int xrow0 = (wm * 64 + l31) * 128;
    const int xrow1 = xrow0 + 32 * 128;
    const int arow  = (wn * 32 + l31) * 128;
    auto phase = [&](const char* AbR, const char* XbR, int kk) {
        const int off = ((kk * 2 + lg) ^ sw3) << 4;
        bf16x8 af0 = *reinterpret_cast<const bf16x8*>(XbR + xrow0 + off);
        bf16x8 af1 = *reinterpret_cast<const bf16x8*>(XbR + xrow1 + off);
        bf16x8 b0  = *reinterpret_cast<const bf16x8*>(AbR + arow + off);
        bf16x8 b1  = *reinterpret_cast<const bf16x8*>(AbR + 8192 + arow + off);
        bf16x8 b2  = *reinterpret_cast<const bf16x8*>(AbR + 16384 + arow + off);
        __builtin_amdgcn_s_setprio(1);
        acc[0][0] = MFMA_B(af0, b0, acc[0][0]); acc[0][1] = MFMA_B(af1, b0, acc[0][1]);
        acc[1][0] = MFMA_B(af0, b1, acc[1][0]); acc[1][1] = MFMA_B(af1, b1, acc[1][1]);
        acc[2][0] = MFMA_B(af0, b2, acc[2][0]); acc[2][1] = MFMA_B(af1, b2, acc[2][1]);
        __builtin_amdgcn_s_setprio(0);
    };
    load_tile(0);
    store_A(Ab0);
    store_X(Xb0);
    load_tile(64);
    asm volatile("s_waitcnt lgkmcnt(0)" ::: "memory");
    __builtin_amdgcn_s_barrier();
    for (int jt2 = 0; jt2 < 8; ++jt2) {
        const int jt = jt2 * 2;
        phase(Ab0, Xb0, 0);
        phase(Ab0, Xb0, 1);
        store_A(Ab1);
        phase(Ab0, Xb0, 2);
        store_X(Xb1);
        phase(Ab0, Xb0, 3);
        if (jt + 2 < 16) load_tile((jt + 2) * 64);
        asm volatile("s_waitcnt lgkmcnt(0)" ::: "memory");
        __builtin_amdgcn_s_barrier();
        phase(Ab1, Xb1, 0);
        phase(Ab1, Xb1, 1);
        if (jt + 1 < 15) store_A(Ab0);
        phase(Ab1, Xb1, 2);
        if (jt + 1 < 15) store_X(Xb0);
        phase(Ab1, Xb1, 3);
        if (jt + 3 < 16) load_tile((jt + 3) * 64);
        asm volatile("s_waitcnt lgkmcnt(0)" ::: "memory");
        __builtin_amdgcn_s_barrier();
    }
    {
        const int fi0 = wid * 3;
        #pragma unroll
        for (int q = 0; q < 3; ++q) {
            int fi = fi0 + q;
            int k  = fi >> 3;
            int mo = (fi >> 2) & 1;
            int s  = fi & 3;
            int o  = 32 * mo + l31;
            int fb = 32 * (s >> 1) + 16 * (s & 1) + 4 * lg;
            bf16x8 v;
            #pragma unroll
            for (int e = 0; e < 8; ++e) {
                int f = fb + (e & 3) + 8 * (e >> 2);
                v[e] = (__bf16)Theta[(k * FF + f) * FF + o];
            }
            *reinterpret_cast<bf16x8*>(lds_raw + (fi * 64 + lane) * 16) = v;
        }
    }
    __syncthreads();
    f32x16 of[2] = {};
    #pragma unroll
    for (int k = 0; k < KC; ++k) {
        #pragma unroll
        for (int s = 0; s < 4; ++s) {
            bf16x8 pb;
            #pragma unroll
            for (int e = 0; e < 8; ++e)
                pb[e] = (__bf16)acc[k][s >> 1][e + 8 * (s & 1)];
            #pragma unroll
            for (int mo = 0; mo < 2; ++mo) {
                bf16x8 th = *reinterpret_cast<const bf16x8*>(
                    lds_raw + ((((k * 2 + mo) * 4 + s) * 64) + lane) * 16);
                of[mo] = MFMA_B(pb, th, of[mo]);
            }
        }
    }
    const int t = t_base + wm;
    float* op = out + (((size_t)b * TT + t) * NN + i_base + wn * 32) * FF;
    #pragma unroll
    for (int mo = 0; mo < 2; ++mo) {
        #pragma unroll
        for (int r = 0; r < 16; ++r) {
            int row = (r & 3) + 8 * (r >> 2) + 4 * lg;
            int o   = 32 * mo + l31;
            float v = of[mo][r];
            op[(size_t)row * FF + o] = v > 0.0f ? v : 0.0f;
        }
    }
}

extern "C" void kernel_launch(void* const* d_in, const int* in_sizes, int n_in,
                              void* d_out, int out_size, void* d_ws, size_t ws_size,
                              hipStream_t stream) {
    const float* x     = (const float*)d_in[0];
    const float* att   = (const float*)d_in[1];
    const float* cheb  = (const float*)d_in[2];
    const float* Theta = (const float*)d_in[3];
    float* out = (float*)d_out;
    (void)in_sizes; (void)n_in; (void)out_size;

    if (ws_size >= T2_BYTES) {
        u16* yfr = (u16*)d_ws;
        u16* cbf = (u16*)((char*)d_ws + YF_BYTES);
        x_to_yfrags<<<dim3(BB * TT * 16), 256, 0, stream>>>(x, yfr);
        cheb_to_bf16<<<dim3(KC * NN * NN / (256 * 8)), 256, 0, stream>>>(cheb, cbf);
        cheb_main_t2<<<dim3(BB * 16 * 3), 512, 0, stream>>>(yfr, att, cbf, Theta, out);
    } else {
        cheb_fused<<<dim3(BB * 16 * 3), 512, 0, stream>>>(x, att, cheb, Theta, out);
    }
}